// Round 7
// baseline (612.297 us; speedup 1.0000x reference)
//
#include <hip/hip_runtime.h>
#include <math.h>

#define N_NODES 100000
#define N_EDGES 1600000
#define IN_F    512
#define HID     128

#define SH      8                       // nodes-per-bin shift
#define NPB     256                     // nodes per bin
#define BINS    ((N_NODES + NPB - 1) / NPB)   // 391
#define CBLK    256                     // edge-chunk blocks
#define EPB     ((N_EDGES + CBLK - 1) / CBLK) // 6250

typedef __attribute__((ext_vector_type(8))) _Float16 half8;
typedef __attribute__((ext_vector_type(4))) float float4v;

// ---------------- pass 1: per-block LDS histograms over dst-bins and src-bins ----------------
__global__ __launch_bounds__(256) void hist_kernel(const int* __restrict__ src,
                                                   const int* __restrict__ dst,
                                                   int* __restrict__ dbh, int* __restrict__ sbh) {
    __shared__ int hd[BINS], hs[BINS];
    const int t = threadIdx.x, blk = blockIdx.x;
    for (int i = t; i < BINS; i += 256) { hd[i] = 0; hs[i] = 0; }
    __syncthreads();
    const int e0 = blk * EPB, e1 = min(N_EDGES, e0 + EPB);
    for (int e = e0 + t; e < e1; e += 256) {
        atomicAdd(&hd[dst[e] >> SH], 1);
        atomicAdd(&hs[src[e] >> SH], 1);
    }
    __syncthreads();
    for (int i = t; i < BINS; i += 256) {
        dbh[i * CBLK + blk] = hd[i];
        sbh[i * CBLK + blk] = hs[i];
    }
}

// ---------------- pass 2a: per-bin exclusive scan over the 256 block counts ----------------
__global__ __launch_bounds__(256) void binscan_kernel(int* __restrict__ dbh, int* __restrict__ sbh,
                                                      int* __restrict__ dtot, int* __restrict__ stot) {
    __shared__ int sh[256];
    const int b = blockIdx.x, t = threadIdx.x;
    int* arr; int* tot;
    if (b < BINS) { arr = dbh + (size_t)b * CBLK; tot = &dtot[b]; }
    else          { arr = sbh + (size_t)(b - BINS) * CBLK; tot = &stot[b - BINS]; }
    int v = arr[t];
    sh[t] = v; __syncthreads();
#pragma unroll
    for (int d = 1; d < 256; d <<= 1) {
        int u = (t >= d) ? sh[t - d] : 0;
        __syncthreads();
        sh[t] += u;
        __syncthreads();
    }
    arr[t] = sh[t] - v;
    if (t == 255) *tot = sh[255];
}

// ---------------- pass 2b: scan bin totals -> bin bases (both sides) ----------------
__global__ __launch_bounds__(512) void binbase_kernel(const int* __restrict__ dtot,
                                                      const int* __restrict__ stot,
                                                      int* __restrict__ dbase, int* __restrict__ sbase,
                                                      int* __restrict__ offs) {
    __shared__ int sh[512];
    const int t = threadIdx.x;
    int v = (t < BINS) ? dtot[t] : 0;
    sh[t] = v; __syncthreads();
#pragma unroll
    for (int d = 1; d < 512; d <<= 1) {
        int u = (t >= d) ? sh[t - d] : 0;
        __syncthreads();
        sh[t] += u;
        __syncthreads();
    }
    if (t < BINS) dbase[t] = sh[t] - v;
    if (t == BINS - 1) { dbase[BINS] = sh[t]; offs[N_NODES] = sh[t]; }
    __syncthreads();
    int v2 = (t < BINS) ? stot[t] : 0;
    sh[t] = v2; __syncthreads();
#pragma unroll
    for (int d = 1; d < 512; d <<= 1) {
        int u = (t >= d) ? sh[t - d] : 0;
        __syncthreads();
        sh[t] += u;
        __syncthreads();
    }
    if (t < BINS) sbase[t] = sh[t] - v2;
    if (t == BINS - 1) sbase[BINS] = sh[t];
}

// ---------------- pass 3: scatter edges into bin-sorted arrays (LDS cursors only) ----------------
__global__ __launch_bounds__(256) void scatter_bins_kernel(const int* __restrict__ src,
                                                           const int* __restrict__ dst,
                                                           const int* __restrict__ dbh,
                                                           const int* __restrict__ sbh,
                                                           const int* __restrict__ dbase,
                                                           const int* __restrict__ sbase,
                                                           int* __restrict__ ds_dst,
                                                           int* __restrict__ ds_src,
                                                           int* __restrict__ ss_src) {
    __shared__ int dcur[BINS], scur[BINS];
    const int t = threadIdx.x, blk = blockIdx.x;
    for (int i = t; i < BINS; i += 256) {
        dcur[i] = dbase[i] + dbh[i * CBLK + blk];
        scur[i] = sbase[i] + sbh[i * CBLK + blk];
    }
    __syncthreads();
    const int e0 = blk * EPB, e1 = min(N_EDGES, e0 + EPB);
    for (int e = e0 + t; e < e1; e += 256) {
        int d = dst[e], s = src[e];
        int p = atomicAdd(&dcur[d >> SH], 1);
        ds_dst[p] = d; ds_src[p] = s;
        int q = atomicAdd(&scur[s >> SH], 1);
        ss_src[q] = s;
    }
}

// ---------------- pass 4: per-bin counting sort -> indeg/offs/norms/CSR ----------------
__global__ __launch_bounds__(256) void finalize_kernel(const int* __restrict__ ds_dst,
                                                       const int* __restrict__ ds_src,
                                                       const int* __restrict__ ss_src,
                                                       const int* __restrict__ dbase,
                                                       const int* __restrict__ sbase,
                                                       int* __restrict__ csr, int* __restrict__ offs,
                                                       float* __restrict__ norm_dst,
                                                       float* __restrict__ norm_src) {
    __shared__ int cnt[NPB], pos[NPB];
    const int t = threadIdx.x, b = blockIdx.x;
    if (b < BINS) {
        const int start = dbase[b], end = dbase[b + 1];
        cnt[t] = 0; __syncthreads();
        for (int k = start + t; k < end; k += 256)
            atomicAdd(&cnt[ds_dst[k] & (NPB - 1)], 1);
        __syncthreads();
        const int c = cnt[t];
        pos[t] = c; __syncthreads();
#pragma unroll
        for (int d = 1; d < 256; d <<= 1) {
            int u = (t >= d) ? pos[t - d] : 0;
            __syncthreads();
            pos[t] += u;
            __syncthreads();
        }
        const int excl = pos[t] - c;
        const int node = (b << SH) + t;
        if (node < N_NODES) {
            offs[node] = start + excl;
            norm_dst[node] = rsqrtf(fmaxf((float)c, 1.0f));
        }
        cnt[t] = start + excl;
        __syncthreads();
        for (int k = start + t; k < end; k += 256) {
            int dl = ds_dst[k] & (NPB - 1);
            int p = atomicAdd(&cnt[dl], 1);
            csr[p] = ds_src[k];
        }
    } else {
        const int bb = b - BINS;
        const int start = sbase[bb], end = sbase[bb + 1];
        cnt[t] = 0; __syncthreads();
        for (int k = start + t; k < end; k += 256)
            atomicAdd(&cnt[ss_src[k] & (NPB - 1)], 1);
        __syncthreads();
        const int node = (bb << SH) + t;
        if (node < N_NODES)
            norm_src[node] = rsqrtf(fmaxf((float)cnt[t], 1.0f));
    }
}

// ---------------- W1 -> f16, transposed to [col][k] ----------------
__global__ void cvtW1_kernel(const float* __restrict__ W1, _Float16* __restrict__ W1T) {
    int i = blockIdx.x * blockDim.x + threadIdx.x;
    if (i < IN_F * HID) {
        int k = i >> 7, c = i & 127;
        W1T[(size_t)c * IN_F + k] = (_Float16)W1[i];
    }
}

// ---------------- GEMM1 via MFMA f16: NO LDS, no barriers, reg-prefetch pipeline ----
// BM=128, BN=128; 4 waves; wave w owns rows [m0+w*32, +32). A loaded straight from X
// (each lane 8 consecutive fp32 per fragment row), B from L2-resident W1T.
__global__ __launch_bounds__(256) void gemm1_mfma_kernel(const float* __restrict__ X,
                                                         const _Float16* __restrict__ W1T,
                                                         const float* __restrict__ norm_src,
                                                         _Float16* __restrict__ xwh) {
    const int t    = threadIdx.x;
    const int wave = t >> 6;
    const int lane = t & 63;
    const int quad = lane >> 4;
    const int l16  = lane & 15;
    const int m0   = blockIdx.x * 128;

    const int row0 = m0 + wave * 32 + l16;
    const int row1 = row0 + 16;
    const bool val0 = row0 < N_NODES;
    const bool val1 = row1 < N_NODES;
    const float* xp0 = X + (size_t)row0 * IN_F + quad * 8;
    const float* xp1 = X + (size_t)row1 * IN_F + quad * 8;
    const _Float16* wp = W1T + quad * 8 + (size_t)l16 * IN_F;

    float4v acc[2][8];
#pragma unroll
    for (int r = 0; r < 2; r++)
#pragma unroll
        for (int c = 0; c < 8; c++) acc[r][c] = (float4v)0.f;

    const float4 fz = make_float4(0.f, 0.f, 0.f, 0.f);

    // prefetch registers for tile kt
    float4 nA[2][2];
    half8  nB[8];

    // load tile 0
    nA[0][0] = val0 ? reinterpret_cast<const float4*>(xp0)[0] : fz;
    nA[0][1] = val0 ? reinterpret_cast<const float4*>(xp0)[1] : fz;
    nA[1][0] = val1 ? reinterpret_cast<const float4*>(xp1)[0] : fz;
    nA[1][1] = val1 ? reinterpret_cast<const float4*>(xp1)[1] : fz;
#pragma unroll
    for (int ct = 0; ct < 8; ct++)
        nB[ct] = *reinterpret_cast<const half8*>(wp + (size_t)ct * 16 * IN_F);

    for (int it = 0; it < IN_F / 32; it++) {
        float4 cA[2][2];
        half8  cB[8];
#pragma unroll
        for (int r = 0; r < 2; r++) { cA[r][0] = nA[r][0]; cA[r][1] = nA[r][1]; }
#pragma unroll
        for (int ct = 0; ct < 8; ct++) cB[ct] = nB[ct];

        // issue next tile's loads (no consumers until next iteration)
        if (it + 1 < IN_F / 32) {
            const int kt = (it + 1) * 32;
            nA[0][0] = val0 ? reinterpret_cast<const float4*>(xp0 + kt)[0] : fz;
            nA[0][1] = val0 ? reinterpret_cast<const float4*>(xp0 + kt)[1] : fz;
            nA[1][0] = val1 ? reinterpret_cast<const float4*>(xp1 + kt)[0] : fz;
            nA[1][1] = val1 ? reinterpret_cast<const float4*>(xp1 + kt)[1] : fz;
#pragma unroll
            for (int ct = 0; ct < 8; ct++)
                nB[ct] = *reinterpret_cast<const half8*>(wp + kt + (size_t)ct * 16 * IN_F);
        }

        // convert current A to f16 fragments
        half8 af[2];
#pragma unroll
        for (int r = 0; r < 2; r++) {
            af[r][0] = (_Float16)cA[r][0].x; af[r][1] = (_Float16)cA[r][0].y;
            af[r][2] = (_Float16)cA[r][0].z; af[r][3] = (_Float16)cA[r][0].w;
            af[r][4] = (_Float16)cA[r][1].x; af[r][5] = (_Float16)cA[r][1].y;
            af[r][6] = (_Float16)cA[r][1].z; af[r][7] = (_Float16)cA[r][1].w;
        }
#pragma unroll
        for (int r = 0; r < 2; r++)
#pragma unroll
            for (int ct = 0; ct < 8; ct++)
                acc[r][ct] = __builtin_amdgcn_mfma_f32_16x16x32_f16(af[r], cB[ct], acc[r][ct], 0, 0, 0);
    }

    // epilogue: scale by norm_src, store f16
#pragma unroll
    for (int r = 0; r < 2; r++) {
#pragma unroll
        for (int i = 0; i < 4; i++) {
            int grow = m0 + wave * 32 + r * 16 + quad * 4 + i;
            if (grow < N_NODES) {
                float s = norm_src[grow];
                _Float16* orow = &xwh[(size_t)grow * HID];
#pragma unroll
                for (int ct = 0; ct < 8; ct++)
                    orow[ct * 16 + l16] = (_Float16)(acc[r][ct][i] * s);
            }
        }
    }
}

// ---------------- fused gather1 + relu + layer2 GEMV: one wave per node ----------------
// lane = (sub, j16): sub = edge slot (4 edges in flight), j16 owns features [j16*8, +8)
__global__ __launch_bounds__(256) void gather1_kernel(
        const int* __restrict__ csr, const int* __restrict__ offs,
        const _Float16* __restrict__ xwh, const float* __restrict__ norm_dst,
        const float* __restrict__ norm_src, const float* __restrict__ b1,
        const float* __restrict__ W2, float* __restrict__ hw2) {
    const int w    = (blockIdx.x * blockDim.x + threadIdx.x) >> 6;
    const int lane = threadIdx.x & 63;
    if (w >= N_NODES) return;
    const int sub = lane >> 4, j16 = lane & 15;
    const int off = offs[w], end = offs[w + 1];

    float acc[8];
#pragma unroll
    for (int i = 0; i < 8; i++) acc[i] = 0.f;

    for (int k = off + sub; k < end; k += 4) {
        int s = csr[k];
        half8 v = *reinterpret_cast<const half8*>(&xwh[(size_t)s * HID + j16 * 8]);
#pragma unroll
        for (int i = 0; i < 8; i++) acc[i] += (float)v[i];
    }
    // fold the 4 edge-groups (lanes differing in bits 4,5 of lane)
#pragma unroll
    for (int i = 0; i < 8; i++) {
        acc[i] += __shfl_xor(acc[i], 16);
        acc[i] += __shfl_xor(acc[i], 32);
    }

    const float nd = norm_dst[w];
    float4 b1a = reinterpret_cast<const float4*>(b1)[j16 * 2];
    float4 b1b = reinterpret_cast<const float4*>(b1)[j16 * 2 + 1];
    float bb[8] = {b1a.x, b1a.y, b1a.z, b1a.w, b1b.x, b1b.y, b1b.z, b1b.w};

    float p0 = 0.f, p1 = 0.f;
#pragma unroll
    for (int i = 0; i < 8; i++) {
        float h = fmaxf(acc[i] * nd + bb[i], 0.f);
        float2 w2 = reinterpret_cast<const float2*>(W2)[j16 * 8 + i];
        p0 += h * w2.x;
        p1 += h * w2.y;
    }
#pragma unroll
    for (int d = 1; d < 16; d <<= 1) {
        p0 += __shfl_xor(p0, d);
        p1 += __shfl_xor(p1, d);
    }
    if (lane == 0) {
        float ns = norm_src[w];
        reinterpret_cast<float2*>(hw2)[w] = make_float2(p0 * ns, p1 * ns);
    }
}

// ---------------- fused gather2 + softmax: 4 nodes per wave (16 lanes each) ----------------
__global__ void gather2_softmax_kernel(
        const int* __restrict__ csr, const int* __restrict__ offs,
        const float* __restrict__ hw2, const float* __restrict__ norm_dst,
        const float* __restrict__ b2, float* __restrict__ out) {
    const int w    = (blockIdx.x * blockDim.x + threadIdx.x) >> 6;
    const int lane = threadIdx.x & 63;
    const int sub  = lane >> 4, k0 = lane & 15;
    const int n = w * 4 + sub;
    if (n >= N_NODES) return;
    const int off = offs[n], end = offs[n + 1];

    float a0 = 0.f, a1 = 0.f;
    for (int k = off + k0; k < end; k += 16) {
        int s = csr[k];
        float2 v = reinterpret_cast<const float2*>(hw2)[s];
        a0 += v.x; a1 += v.y;
    }
#pragma unroll
    for (int d = 1; d < 16; d <<= 1) {
        a0 += __shfl_xor(a0, d);
        a1 += __shfl_xor(a1, d);
    }
    if (k0 == 0) {
        float nd = norm_dst[n];
        float z0 = a0 * nd + b2[0];
        float z1 = a1 * nd + b2[1];
        float m = fmaxf(z0, z1);
        float e0 = expf(z0 - m), e1 = expf(z1 - m);
        float inv = 1.f / (e0 + e1);
        reinterpret_cast<float2*>(out)[n] = make_float2(e0 * inv, e1 * inv);
    }
}

extern "C" void kernel_launch(void* const* d_in, const int* in_sizes, int n_in,
                              void* d_out, int out_size, void* d_ws, size_t ws_size,
                              hipStream_t stream) {
    const float* X   = (const float*)d_in[0];
    const float* W1  = (const float*)d_in[1];
    const float* b1  = (const float*)d_in[2];
    const float* W2  = (const float*)d_in[3];
    const float* b2  = (const float*)d_in[4];
    const int*   src = (const int*)d_in[5];
    const int*   dst = (const int*)d_in[6];
    float* out = (float*)d_out;

    const size_t N = N_NODES;
    char* ws = (char*)d_ws;
    int*   dbh      = (int*)ws;   ws += (size_t)BINS * CBLK * 4;
    int*   sbh      = (int*)ws;   ws += (size_t)BINS * CBLK * 4;
    int*   dtot     = (int*)ws;   ws += BINS * 4;
    int*   stot     = (int*)ws;   ws += BINS * 4;
    int*   dbase    = (int*)ws;   ws += (BINS + 1) * 4;
    int*   sbase    = (int*)ws;   ws += (BINS + 1) * 4;
    int*   ds_dst   = (int*)ws;   ws += (size_t)N_EDGES * 4;
    int*   ds_src   = (int*)ws;   ws += (size_t)N_EDGES * 4;
    int*   ss_src   = (int*)ws;   ws += (size_t)N_EDGES * 4;
    int*   csr      = (int*)ws;   ws += (size_t)N_EDGES * 4;
    int*   offs     = (int*)ws;   ws += (N + 1) * 4;
    float* norm_src = (float*)ws; ws += N * 4;
    float* norm_dst = (float*)ws; ws += N * 4;
    float* hw2      = (float*)ws; ws += N * 2 * 4;
    _Float16* W1T   = (_Float16*)ws; ws += (size_t)IN_F * HID * 2;
    _Float16* xwh   = (_Float16*)ws; ws += N * (size_t)HID * 2;

    hist_kernel<<<CBLK, 256, 0, stream>>>(src, dst, dbh, sbh);
    binscan_kernel<<<2 * BINS, 256, 0, stream>>>(dbh, sbh, dtot, stot);
    binbase_kernel<<<1, 512, 0, stream>>>(dtot, stot, dbase, sbase, offs);
    scatter_bins_kernel<<<CBLK, 256, 0, stream>>>(src, dst, dbh, sbh, dbase, sbase,
                                                  ds_dst, ds_src, ss_src);
    finalize_kernel<<<2 * BINS, 256, 0, stream>>>(ds_dst, ds_src, ss_src, dbase, sbase,
                                                  csr, offs, norm_dst, norm_src);
    cvtW1_kernel<<<(IN_F * HID + 255) / 256, 256, 0, stream>>>(W1, W1T);
    gemm1_mfma_kernel<<<(N_NODES + 127) / 128, 256, 0, stream>>>(X, W1T, norm_src, xwh);
    gather1_kernel<<<(N_NODES * 64 + 255) / 256, 256, 0, stream>>>(
        csr, offs, xwh, norm_dst, norm_src, b1, W2, hw2);
    gather2_softmax_kernel<<<(((int)N + 3) / 4 * 64 + 255) / 256, 256, 0, stream>>>(
        csr, offs, hw2, norm_dst, b2, out);
}